// Round 5
// baseline (268.403 us; speedup 1.0000x reference)
//
#include <hip/hip_runtime.h>
#include <hip/hip_bf16.h>
#include <math.h>

#define Bn 16
#define Ln 512
#define Dn 1024
#define Pn 10

typedef short bf16x8 __attribute__((ext_vector_type(8)));
typedef float f32x4 __attribute__((ext_vector_type(4)));

// Split fp32 -> (hi, lo) bf16 bit-patterns. a ~= hi + lo to ~2^-17 rel.
__device__ __forceinline__ short2 bf16split(float x) {
    __hip_bfloat16 h = __float2bfloat16(x);
    float hf = __bfloat162float(h);
    __hip_bfloat16 l = __float2bfloat16(x - hf);
    short2 r;
    __builtin_memcpy(&r.x, &h, 2);
    __builtin_memcpy(&r.y, &l, 2);
    return r;
}

// ---------------------------------------------------------------------------
// Kernel 1: row L2 norms. Rows 0..8191 = sent1, 8192..16383 = sent2.
// ---------------------------------------------------------------------------
__global__ __launch_bounds__(256) void norms_kernel(const float* __restrict__ s1,
                                                    const float* __restrict__ s2,
                                                    float* __restrict__ nrm) {
    const int wave = threadIdx.x >> 6;
    const int lane = threadIdx.x & 63;
    const int row  = blockIdx.x * 4 + wave;
    const float* src = (row < Bn * Ln) ? (s1 + (size_t)row * Dn)
                                       : (s2 + (size_t)(row - Bn * Ln) * Dn);
    const float4* p4 = (const float4*)src;
    float acc = 0.f;
#pragma unroll
    for (int i = 0; i < 4; ++i) {
        float4 v = p4[lane + i * 64];
        acc = fmaf(v.x, v.x, acc);
        acc = fmaf(v.y, v.y, acc);
        acc = fmaf(v.z, v.z, acc);
        acc = fmaf(v.w, v.w, acc);
    }
#pragma unroll
    for (int m = 32; m; m >>= 1) acc += __shfl_xor(acc, m, 64);
    if (lane == 0) nrm[row] = sqrtf(acc);
}

// ---------------------------------------------------------------------------
// Kernel 2: s2 fp32 -> bf16 hi/lo, normal layout [B*L2][D]. 8 elems/thread.
// ---------------------------------------------------------------------------
__global__ __launch_bounds__(256) void cvt_s2n_kernel(const float* __restrict__ s2,
                                                      short* __restrict__ s2h,
                                                      short* __restrict__ s2l) {
    const size_t i8 = ((size_t)blockIdx.x * 256 + threadIdx.x) * 8;
    float4 v0 = *(const float4*)(s2 + i8);
    float4 v1 = *(const float4*)(s2 + i8 + 4);
    float f[8] = {v0.x, v0.y, v0.z, v0.w, v1.x, v1.y, v1.z, v1.w};
    bf16x8 hv, lv;
#pragma unroll
    for (int j = 0; j < 8; ++j) {
        short2 p = bf16split(f[j]);
        hv[j] = p.x;
        lv[j] = p.y;
    }
    *(bf16x8*)(s2h + i8) = hv;
    *(bf16x8*)(s2l + i8) = lv;
}

// ---------------------------------------------------------------------------
// Kernel 3: s2 fp32 [B][L2][D] -> bf16 hi/lo TRANSPOSED [B][D][L2].
// 64x64 LDS-tiled transpose; block = 256 thr.
// ---------------------------------------------------------------------------
__global__ __launch_bounds__(256) void tr_s2_kernel(const float* __restrict__ s2,
                                                    short* __restrict__ s2th,
                                                    short* __restrict__ s2tl) {
    __shared__ float tile[64][65];
    const int tid = threadIdx.x;
    const int tb  = blockIdx.x;          // 16 b * 8 l2tiles * 16 dtiles
    const int b   = tb >> 7;
    const int rem = tb & 127;
    const int l2c = (rem >> 4) * 64;
    const int dc  = (rem & 15) * 64;

#pragma unroll
    for (int i = 0; i < 4; ++i) {
        int r  = (tid >> 4) + 16 * i;                 // 0..63 (l2 within tile)
        int c4 = (tid & 15) * 4;                      // 0..60 (d within tile)
        float4 v = *(const float4*)(s2 + ((size_t)b * Ln + l2c + r) * Dn + dc + c4);
        tile[r][c4 + 0] = v.x;
        tile[r][c4 + 1] = v.y;
        tile[r][c4 + 2] = v.z;
        tile[r][c4 + 3] = v.w;
    }
    __syncthreads();
#pragma unroll
    for (int i = 0; i < 2; ++i) {
        int dr  = (tid >> 3) + 32 * i;                // 0..63 (d within tile)
        int l2o = (tid & 7) * 8;                      // 0..56 (l2 within tile)
        bf16x8 hv, lv;
#pragma unroll
        for (int j = 0; j < 8; ++j) {
            short2 p = bf16split(tile[l2o + j][dr]);
            hv[j] = p.x;
            lv[j] = p.y;
        }
        size_t off = ((size_t)b * Dn + dc + dr) * Ln + l2c + l2o;
        *(bf16x8*)(s2th + off) = hv;
        *(bf16x8*)(s2tl + off) = lv;
    }
}

// ---------------------------------------------------------------------------
// Kernel 4 (MFMA path): fused cos-matrix -> mean-attentive stats -> output.
// Grid 256 (16 b x 16 row-tiles of 32), block 512 thr (8 waves) = 1 block/CU.
// Phase A: S[32][512] = s1 @ s2^T, split-bf16 3-term MFMA, K=1024.
//   A-frags: s1 fp32 from global, split in-reg (reused over 4 n-tiles).
//   B-frags: pre-converted bf16 hi/lo, direct global->reg (L2-resident).
// Phase B: ws = cos @ s2 over K=l2=512; B from pre-transposed bf16 arrays.
//   ws never materialized: folded into ss=sum ws^2, sd=sum s1*ws per row.
// A/B fragments use the SAME k-mapping (k = (lane>>4)*8+j) so any hw
// k-permutation cancels; C/D layout col=lane&15,row=(lane>>4)*4+reg (m89).
// ---------------------------------------------------------------------------
__global__ __launch_bounds__(512, 2) void mfma_fused_kernel(
        const float* __restrict__ s1, const float* __restrict__ s2,
        const float* __restrict__ kern, const float* __restrict__ nrm,
        const short* __restrict__ s2nh, const short* __restrict__ s2nl,
        const short* __restrict__ s2th, const short* __restrict__ s2tl,
        float* __restrict__ out) {
    __shared__ float Sr[32][516];        // 66 KB: raw dot, then cos
    __shared__ float n2c[Ln];
    __shared__ float n1c[32];
    __shared__ float scl[32];
    __shared__ float red[32][16];
    __shared__ float redS[32][8];
    __shared__ float redD[32][8];
    __shared__ float kc_[16];

    const int tid  = threadIdx.x;
    const int w    = tid >> 6;           // wave 0..7
    const int lane = tid & 63;
    const int lr   = lane & 15;          // row-in-tile (A) / col-in-tile (B,D)
    const int lg   = lane >> 4;          // k-octet group 0..3

    // XCD-aware bijective swizzle: 256 wg = 8 XCD x 32; 16 wg per batch.
    const int wg = ((blockIdx.x & 7) << 5) | (blockIdx.x >> 3);
    const int b  = wg >> 4;
    const int R0 = (wg & 15) * 32;

    const float* s1b = s1 + ((size_t)b * Ln + R0) * Dn;   // [32][1024]
    const size_t s2row0 = (size_t)b * Ln;                 // row base in s2n
    const size_t s2trow0 = (size_t)b * Dn;                // row base in s2t

    if (tid < 32) n1c[tid] = nrm[b * Ln + R0 + tid];
    if (tid < Ln) n2c[tid] = nrm[Bn * Ln + b * Ln + tid];
    if (tid < Pn) kc_[tid] = kern[tid];

    // ---------------- Phase A: S = s1_tile @ s2^T (K = D = 1024) -----------
    f32x4 accA[2][4];
#pragma unroll
    for (int m = 0; m < 2; ++m)
#pragma unroll
        for (int t = 0; t < 4; ++t) accA[m][t] = (f32x4){0.f, 0.f, 0.f, 0.f};

    for (int kc = 0; kc < Dn; kc += 32) {
        bf16x8 ah[2], al[2];
#pragma unroll
        for (int m = 0; m < 2; ++m) {
            const float* ap = s1b + (size_t)(m * 16 + lr) * Dn + kc + lg * 8;
            float4 v0 = *(const float4*)ap;
            float4 v1 = *(const float4*)(ap + 4);
            float f[8] = {v0.x, v0.y, v0.z, v0.w, v1.x, v1.y, v1.z, v1.w};
#pragma unroll
            for (int j = 0; j < 8; ++j) {
                short2 p = bf16split(f[j]);
                ah[m][j] = p.x;
                al[m][j] = p.y;
            }
        }
#pragma unroll
        for (int t = 0; t < 4; ++t) {
            int l2 = (w * 4 + t) * 16 + lr;
            size_t off = (s2row0 + l2) * Dn + kc + lg * 8;
            bf16x8 bh = *(const bf16x8*)(s2nh + off);
            bf16x8 bl = *(const bf16x8*)(s2nl + off);
#pragma unroll
            for (int m = 0; m < 2; ++m) {
                accA[m][t] = __builtin_amdgcn_mfma_f32_16x16x32_bf16(ah[m], bh, accA[m][t], 0, 0, 0);
                accA[m][t] = __builtin_amdgcn_mfma_f32_16x16x32_bf16(ah[m], bl, accA[m][t], 0, 0, 0);
                accA[m][t] = __builtin_amdgcn_mfma_f32_16x16x32_bf16(al[m], bh, accA[m][t], 0, 0, 0);
            }
        }
    }
    // D layout: col = lane&15, row = (lane>>4)*4 + reg  [measured m89/m91]
#pragma unroll
    for (int m = 0; m < 2; ++m)
#pragma unroll
        for (int t = 0; t < 4; ++t)
#pragma unroll
            for (int reg = 0; reg < 4; ++reg)
                Sr[m * 16 + lg * 4 + reg][(w * 4 + t) * 16 + lr] = accA[m][t][reg];
    __syncthreads();

    // ---------------- convert to cos + row sums ----------------------------
    {
        int r = tid >> 4, part = tid & 15;
        float n1v = n1c[r];
        float s = 0.f;
#pragma unroll 8
        for (int j = 0; j < 32; ++j) {
            int l2 = part + 16 * j;
            float d = Sr[r][l2];
            float c = d / fmaxf(n1v * n2c[l2], 1e-8f);
            Sr[r][l2] = c;
            s += c;
        }
        red[r][part] = s;
    }
    __syncthreads();
    if (tid < 32) {
        float s = 0.f;
#pragma unroll
        for (int j = 0; j < 16; ++j) s += red[tid][j];
        scl[tid] = s + 1e-8f;
    }
    __syncthreads();

    // ---------------- Phase B: ws = cos @ s2 (K = L2 = 512) ----------------
    f32x4 accB[2][8];
#pragma unroll
    for (int m = 0; m < 2; ++m)
#pragma unroll
        for (int t = 0; t < 8; ++t) accB[m][t] = (f32x4){0.f, 0.f, 0.f, 0.f};

    for (int kc = 0; kc < Ln; kc += 32) {
        bf16x8 ah[2], al[2];
#pragma unroll
        for (int m = 0; m < 2; ++m) {
            const float* ap = &Sr[m * 16 + lr][kc + lg * 8];
            float4 v0 = *(const float4*)ap;
            float4 v1 = *(const float4*)(ap + 4);
            float f[8] = {v0.x, v0.y, v0.z, v0.w, v1.x, v1.y, v1.z, v1.w};
#pragma unroll
            for (int j = 0; j < 8; ++j) {
                short2 p = bf16split(f[j]);
                ah[m][j] = p.x;
                al[m][j] = p.y;
            }
        }
#pragma unroll
        for (int t = 0; t < 8; ++t) {
            int d = (w * 8 + t) * 16 + lr;
            size_t off = (s2trow0 + d) * Ln + kc + lg * 8;
            bf16x8 bh = *(const bf16x8*)(s2th + off);
            bf16x8 bl = *(const bf16x8*)(s2tl + off);
#pragma unroll
            for (int m = 0; m < 2; ++m) {
                accB[m][t] = __builtin_amdgcn_mfma_f32_16x16x32_bf16(ah[m], bh, accB[m][t], 0, 0, 0);
                accB[m][t] = __builtin_amdgcn_mfma_f32_16x16x32_bf16(ah[m], bl, accB[m][t], 0, 0, 0);
                accB[m][t] = __builtin_amdgcn_mfma_f32_16x16x32_bf16(al[m], bh, accB[m][t], 0, 0, 0);
            }
        }
    }

    // ---------------- fold ws into ss/sd, reduce, epilogue -----------------
    float ss[2][4], sd[2][4];
#pragma unroll
    for (int m = 0; m < 2; ++m)
#pragma unroll
        for (int reg = 0; reg < 4; ++reg) { ss[m][reg] = 0.f; sd[m][reg] = 0.f; }

#pragma unroll
    for (int m = 0; m < 2; ++m)
#pragma unroll
        for (int t = 0; t < 8; ++t) {
            int d = (w * 8 + t) * 16 + lr;
#pragma unroll
            for (int reg = 0; reg < 4; ++reg) {
                int row = m * 16 + lg * 4 + reg;
                float wv = accB[m][t][reg];
                ss[m][reg] = fmaf(wv, wv, ss[m][reg]);
                float x = s1b[(size_t)row * Dn + d];
                sd[m][reg] = fmaf(x, wv, sd[m][reg]);
            }
        }
#pragma unroll
    for (int m = 0; m < 2; ++m)
#pragma unroll
        for (int reg = 0; reg < 4; ++reg) {
#pragma unroll
            for (int msk = 8; msk; msk >>= 1) {
                ss[m][reg] += __shfl_xor(ss[m][reg], msk, 64);
                sd[m][reg] += __shfl_xor(sd[m][reg], msk, 64);
            }
        }
    if (lr == 0) {
#pragma unroll
        for (int m = 0; m < 2; ++m)
#pragma unroll
            for (int reg = 0; reg < 4; ++reg) {
                redS[m * 16 + lg * 4 + reg][w] = ss[m][reg];
                redD[m * 16 + lg * 4 + reg][w] = sd[m][reg];
            }
    }
    __syncthreads();

    if (tid < 32 * Pn) {
        int r = tid / Pn, p = tid % Pn;
        float ssT = 0.f, sdT = 0.f;
#pragma unroll
        for (int j = 0; j < 8; ++j) { ssT += redS[r][j]; sdT += redD[r][j]; }
        float n1v = n1c[r];
        float scv = scl[r];
        float kp  = kc_[p];
        float kp2 = kp * kp;
        float wsn = sqrtf(ssT);
        float dot2  = kp2 * sdT / scv;
        float denom = fmaxf(kp2 * n1v * wsn / fabsf(scv), 1e-8f);
        out[(size_t)(b * Ln + R0 + r) * Pn + p] = dot2 / denom;
    }
}

// ===========================================================================
// fp32 fallback (audited round-1 kernel) — used if ws_size can't hold the
// bf16 pre-converted arrays.
// ===========================================================================
#define Mr 16
#define LD2 516

__global__ __launch_bounds__(256, 2) void fused_kernel(const float* __restrict__ s1,
                                                       const float* __restrict__ s2,
                                                       const float* __restrict__ kern,
                                                       const float* __restrict__ nrm,
                                                       float* __restrict__ out) {
    __shared__ float Sr[Mr][LD2];
    __shared__ float s2t[16][LD2];
    __shared__ float ab[16][16];
    __shared__ float n2c[Ln];
    __shared__ float n1c[Mr];
    __shared__ float scl[Mr];
    __shared__ float red[Mr][16];
    __shared__ float redS[Mr][2];
    __shared__ float redD[Mr][2];
    __shared__ float kc_[16];

    const int tid  = threadIdx.x;
    const int w    = tid >> 6;
    const int lane = tid & 63;
    const int rg   = w & 1;
    const int cg   = w >> 1;

    const int wg = ((blockIdx.x & 7) << 6) | (blockIdx.x >> 3);
    const int b  = wg >> 5;
    const int R0 = (wg & 31) * Mr;

    const float* s1b = s1 + ((size_t)b * Ln + R0) * Dn;
    const float* s2g = s2 + (size_t)b * Ln * Dn;

    if (tid < Mr) n1c[tid] = nrm[b * Ln + R0 + tid];
    n2c[tid]       = nrm[Bn * Ln + b * Ln + tid];
    n2c[tid + 256] = nrm[Bn * Ln + b * Ln + tid + 256];
    if (tid < Pn) kc_[tid] = kern[tid];

    float accA[8][4];
#pragma unroll
    for (int e = 0; e < 8; ++e)
#pragma unroll
        for (int c = 0; c < 4; ++c) accA[e][c] = 0.f;

    for (int kc = 0; kc < Dn; kc += 16) {
        __syncthreads();
        {
            int r = tid >> 4, k = tid & 15;
            ab[k][r] = s1b[(size_t)r * Dn + kc + k];
        }
        {
            int p = tid >> 2, j = tid & 3;
#pragma unroll
            for (int ri = 0; ri < 8; ++ri) {
                int l2 = ri * 64 + p;
                float4 v = *(const float4*)(s2g + (size_t)l2 * Dn + kc + 4 * j);
                s2t[4 * j + 0][l2] = v.x;
                s2t[4 * j + 1][l2] = v.y;
                s2t[4 * j + 2][l2] = v.z;
                s2t[4 * j + 3][l2] = v.w;
            }
        }
        __syncthreads();
#pragma unroll
        for (int k = 0; k < 16; ++k) {
            float4 a0 = *(const float4*)&ab[k][rg * 8];
            float4 a1 = *(const float4*)&ab[k][rg * 8 + 4];
            float4 bv = *(const float4*)&s2t[k][cg * 256 + 4 * lane];
            float aa[8] = {a0.x, a0.y, a0.z, a0.w, a1.x, a1.y, a1.z, a1.w};
            float bb[4] = {bv.x, bv.y, bv.z, bv.w};
#pragma unroll
            for (int e = 0; e < 8; ++e)
#pragma unroll
                for (int c = 0; c < 4; ++c)
                    accA[e][c] = fmaf(aa[e], bb[c], accA[e][c]);
        }
    }
#pragma unroll
    for (int e = 0; e < 8; ++e)
        *(float4*)&Sr[rg * 8 + e][cg * 256 + 4 * lane] =
            make_float4(accA[e][0], accA[e][1], accA[e][2], accA[e][3]);
    __syncthreads();

    {
        int r = tid >> 4, part = tid & 15;
        float n1v = n1c[r];
        float s = 0.f;
#pragma unroll 8
        for (int j = 0; j < 32; ++j) {
            int l2 = part + 16 * j;
            float d = Sr[r][l2];
            float c = d / fmaxf(n1v * n2c[l2], 1e-8f);
            Sr[r][l2] = c;
            s += c;
        }
        red[r][part] = s;
    }
    __syncthreads();
    if (tid < Mr) {
        float s = 0.f;
#pragma unroll
        for (int j = 0; j < 16; ++j) s += red[tid][j];
        scl[tid] = s + 1e-8f;
    }

    float ss[8] = {0.f, 0.f, 0.f, 0.f, 0.f, 0.f, 0.f, 0.f};
    float sd[8] = {0.f, 0.f, 0.f, 0.f, 0.f, 0.f, 0.f, 0.f};

    for (int dh = 0; dh < Dn; dh += 512) {
        float accB[8][4];
#pragma unroll
        for (int e = 0; e < 8; ++e)
#pragma unroll
            for (int c = 0; c < 4; ++c) accB[e][c] = 0.f;

        for (int l2c = 0; l2c < Ln; l2c += 16) {
            __syncthreads();
            {
                int l2 = tid >> 4, r = tid & 15;
                ab[l2][r] = Sr[r][l2c + l2];
            }
            {
                int l2 = tid >> 4, q = tid & 15;
                const float* srcrow = s2g + (size_t)(l2c + l2) * Dn + dh;
#pragma unroll
                for (int j = 0; j < 8; ++j)
                    *(float4*)&s2t[l2][q * 4 + j * 64] =
                        *(const float4*)(srcrow + q * 4 + j * 64);
            }
            __syncthreads();
#pragma unroll
            for (int k = 0; k < 16; ++k) {
                float4 a0 = *(const float4*)&ab[k][rg * 8];
                float4 a1 = *(const float4*)&ab[k][rg * 8 + 4];
                float4 bv = *(const float4*)&s2t[k][cg * 256 + 4 * lane];
                float aa[8] = {a0.x, a0.y, a0.z, a0.w, a1.x, a1.y, a1.z, a1.w};
                float bb[4] = {bv.x, bv.y, bv.z, bv.w};
#pragma unroll
                for (int e = 0; e < 8; ++e)
#pragma unroll
                    for (int c = 0; c < 4; ++c)
                        accB[e][c] = fmaf(aa[e], bb[c], accB[e][c]);
            }
        }
#pragma unroll
        for (int e = 0; e < 8; ++e) {
            const float* s1row = s1b + (size_t)(rg * 8 + e) * Dn + dh + cg * 256 + 4 * lane;
            float4 x = *(const float4*)s1row;
            float xx[4] = {x.x, x.y, x.z, x.w};
#pragma unroll
            for (int c = 0; c < 4; ++c) {
                float wv = accB[e][c];
                ss[e] = fmaf(wv, wv, ss[e]);
                sd[e] = fmaf(xx[c], wv, sd[e]);
            }
        }
    }

#pragma unroll
    for (int e = 0; e < 8; ++e) {
#pragma unroll
        for (int m = 32; m; m >>= 1) {
            ss[e] += __shfl_xor(ss[e], m, 64);
            sd[e] += __shfl_xor(sd[e], m, 64);
        }
    }
    if (lane == 0) {
#pragma unroll
        for (int e = 0; e < 8; ++e) {
            redS[rg * 8 + e][cg] = ss[e];
            redD[rg * 8 + e][cg] = sd[e];
        }
    }
    __syncthreads();

    if (tid < Mr * Pn) {
        int r = tid / Pn, p = tid % Pn;
        float ssT = redS[r][0] + redS[r][1];
        float sdT = redD[r][0] + redD[r][1];
        float n1v = n1c[r];
        float scv = scl[r];
        float kp  = kc_[p];
        float kp2 = kp * kp;
        float wsn = sqrtf(ssT);
        float dot2  = kp2 * sdT / scv;
        float denom = fmaxf(kp2 * n1v * wsn / fabsf(scv), 1e-8f);
        out[(size_t)(b * Ln + R0 + r) * Pn + p] = dot2 / denom;
    }
}

extern "C" void kernel_launch(void* const* d_in, const int* in_sizes, int n_in,
                              void* d_out, int out_size, void* d_ws, size_t ws_size,
                              hipStream_t stream) {
    const float* s1   = (const float*)d_in[0];
    const float* s2   = (const float*)d_in[1];
    const float* kern = (const float*)d_in[2];
    float* out = (float*)d_out;

    char* w = (char*)d_ws;
    float* nrm = (float*)w;                               // 64 KB
    const size_t SZ1 = (size_t)Bn * Ln * Dn * sizeof(short);  // 16 MB per array
    short* s2nh = (short*)(w + 65536);
    short* s2nl = (short*)(w + 65536 + SZ1);
    short* s2th = (short*)(w + 65536 + 2 * SZ1);
    short* s2tl = (short*)(w + 65536 + 3 * SZ1);
    const size_t NEED = 65536 + 4 * SZ1;                  // ~64.1 MB

    hipLaunchKernelGGL(norms_kernel, dim3((Bn * Ln * 2) / 4), dim3(256), 0, stream,
                       s1, s2, nrm);

    if (ws_size >= NEED) {
        // MFMA path
        hipLaunchKernelGGL(cvt_s2n_kernel, dim3((Bn * Ln * Dn) / (256 * 8)), dim3(256),
                           0, stream, s2, s2nh, s2nl);
        hipLaunchKernelGGL(tr_s2_kernel, dim3(Bn * 8 * 16), dim3(256), 0, stream,
                           s2, s2th, s2tl);
        hipLaunchKernelGGL(mfma_fused_kernel, dim3(Bn * (Ln / 32)), dim3(512), 0, stream,
                           s1, s2, kern, nrm, s2nh, s2nl, s2th, s2tl, out);
    } else {
        // fp32 fallback
        hipLaunchKernelGGL(fused_kernel, dim3(Bn * (Ln / Mr)), dim3(256), 0, stream,
                           s1, s2, kern, nrm, out);
    }
}

// Round 7
// 230.468 us; speedup vs baseline: 1.1646x; 1.1646x over previous
//
#include <hip/hip_runtime.h>
#include <hip/hip_bf16.h>
#include <math.h>

#define Bn 16
#define Ln 512
#define Dn 1024
#define Pn 10

typedef short bf16x8 __attribute__((ext_vector_type(8)));
typedef float f32x4 __attribute__((ext_vector_type(4)));

// Split fp32 -> (hi, lo) bf16 bit-patterns. a ~= hi + lo to ~2^-17 rel.
__device__ __forceinline__ short2 bf16split(float x) {
    __hip_bfloat16 h = __float2bfloat16(x);
    float hf = __bfloat162float(h);
    __hip_bfloat16 l = __float2bfloat16(x - hf);
    short2 r;
    __builtin_memcpy(&r.x, &h, 2);
    __builtin_memcpy(&r.y, &l, 2);
    return r;
}

// ---------------------------------------------------------------------------
// Kernel 1: row L2 norms. Rows 0..8191 = sent1, 8192..16383 = sent2.
// ---------------------------------------------------------------------------
__global__ __launch_bounds__(256) void norms_kernel(const float* __restrict__ s1,
                                                    const float* __restrict__ s2,
                                                    float* __restrict__ nrm) {
    const int wave = threadIdx.x >> 6;
    const int lane = threadIdx.x & 63;
    const int row  = blockIdx.x * 4 + wave;
    const float* src = (row < Bn * Ln) ? (s1 + (size_t)row * Dn)
                                       : (s2 + (size_t)(row - Bn * Ln) * Dn);
    const float4* p4 = (const float4*)src;
    float acc = 0.f;
#pragma unroll
    for (int i = 0; i < 4; ++i) {
        float4 v = p4[lane + i * 64];
        acc = fmaf(v.x, v.x, acc);
        acc = fmaf(v.y, v.y, acc);
        acc = fmaf(v.z, v.z, acc);
        acc = fmaf(v.w, v.w, acc);
    }
#pragma unroll
    for (int m = 32; m; m >>= 1) acc += __shfl_xor(acc, m, 64);
    if (lane == 0) nrm[row] = sqrtf(acc);
}

// ---------------------------------------------------------------------------
// Kernel 2 (merged cvt+tr): s2 fp32 [B][L2][D] -> bf16 hi/lo in BOTH layouts:
// normal [B*L2][D] and transposed [B][D][L2]. One read of s2, 64x64 tiles.
// ---------------------------------------------------------------------------
__global__ __launch_bounds__(256) void prep_s2_kernel(const float* __restrict__ s2,
                                                      short* __restrict__ s2nh,
                                                      short* __restrict__ s2nl,
                                                      short* __restrict__ s2th,
                                                      short* __restrict__ s2tl) {
    __shared__ float tile[64][65];
    const int tid = threadIdx.x;
    const int tb  = blockIdx.x;          // 16 b * 8 l2tiles * 16 dtiles
    const int b   = tb >> 7;
    const int rem = tb & 127;
    const int l2c = (rem >> 4) * 64;
    const int dc  = (rem & 15) * 64;

#pragma unroll
    for (int i = 0; i < 4; ++i) {
        int r  = (tid >> 4) + 16 * i;                 // l2 within tile
        int c4 = (tid & 15) * 4;                      // d within tile
        float4 v = *(const float4*)(s2 + ((size_t)b * Ln + l2c + r) * Dn + dc + c4);
        tile[r][c4 + 0] = v.x;
        tile[r][c4 + 1] = v.y;
        tile[r][c4 + 2] = v.z;
        tile[r][c4 + 3] = v.w;
        // normal-layout split write (8B per plane)
        short2 p0 = bf16split(v.x), p1 = bf16split(v.y),
               p2 = bf16split(v.z), p3 = bf16split(v.w);
        short4 h; h.x = p0.x; h.y = p1.x; h.z = p2.x; h.w = p3.x;
        short4 l; l.x = p0.y; l.y = p1.y; l.z = p2.y; l.w = p3.y;
        size_t noff = ((size_t)b * Ln + l2c + r) * Dn + dc + c4;
        *(short4*)(s2nh + noff) = h;
        *(short4*)(s2nl + noff) = l;
    }
    __syncthreads();
#pragma unroll
    for (int i = 0; i < 2; ++i) {
        int dr  = (tid >> 3) + 32 * i;                // d within tile
        int l2o = (tid & 7) * 8;                      // l2 within tile
        bf16x8 hv, lv;
#pragma unroll
        for (int j = 0; j < 8; ++j) {
            short2 p = bf16split(tile[l2o + j][dr]);
            hv[j] = p.x;
            lv[j] = p.y;
        }
        size_t off = ((size_t)b * Dn + dc + dr) * Ln + l2c + l2o;
        *(bf16x8*)(s2th + off) = hv;
        *(bf16x8*)(s2tl + off) = lv;
    }
}

// ---------------------------------------------------------------------------
// Kernel 3 (MFMA path v2): fused cos-matrix -> mean-attentive stats -> output.
// Grid 256 (16 b x 16 row-tiles of 32), block 1024 thr (16 waves) = 46% occ.
// Phase A: S[32][512] = s1 @ s2^T, split-bf16 3-term MFMA, K=1024.
//   A staged via LDS as pre-split bf16 hi/lo planes, double-buffered per
//   128-k chunk (1 barrier / 128 k so B prefetch survives the drain).
//   B: pre-converted bf16 hi/lo, direct global->reg (L2/LLC-resident).
// Phase B: ws = cos @ s2 over K=l2=512 (no barriers in loop); ws never
//   materialized: folded into ss=sum ws^2, sd=sum s1*ws per row.
// A/B fragments use SAME k-mapping (k=(lane>>4)*8+j); C/D layout
// col=lane&15, row=(lane>>4)*4+reg (m89/m91).
// ---------------------------------------------------------------------------
__global__ __launch_bounds__(1024, 4) void mfma_fused_kernel(
        const float* __restrict__ s1,
        const float* __restrict__ kern, const float* __restrict__ nrm,
        const short* __restrict__ s2nh, const short* __restrict__ s2nl,
        const short* __restrict__ s2th, const short* __restrict__ s2tl,
        float* __restrict__ out) {
    __shared__ float Sr[32][516];        // 66 KB: raw dot, then cos
    __shared__ short Ah[2][32][136];     // 17 KB: A hi plane, dbuf, 128-k slice
    __shared__ short Al[2][32][136];     // 17 KB: A lo plane
    __shared__ float n2c[Ln];
    __shared__ float n1c[32];
    __shared__ float scl[32];
    __shared__ float red[32][32];
    __shared__ float redS[32][16];
    __shared__ float redD[32][16];
    __shared__ float kc_[16];

    const int tid  = threadIdx.x;
    const int w    = tid >> 6;           // wave 0..15
    const int lane = tid & 63;
    const int lr   = lane & 15;          // row-in-tile (A) / col-in-tile (B,D)
    const int lg   = lane >> 4;          // k-octet group 0..3

    // XCD-aware bijective swizzle: 256 wg = 8 XCD x 32; 16 wg per batch.
    const int wg = ((blockIdx.x & 7) << 5) | (blockIdx.x >> 3);
    const int b  = wg >> 4;
    const int R0 = (wg & 15) * 32;

    const float* s1b = s1 + ((size_t)b * Ln + R0) * Dn;   // [32][1024]
    const size_t s2row0  = (size_t)b * Ln;                // row base in s2n
    const size_t s2trow0 = (size_t)b * Dn;                // row base in s2t

    if (tid < 32) n1c[tid] = nrm[b * Ln + R0 + tid];
    if (tid < Ln) n2c[tid] = nrm[Bn * Ln + b * Ln + tid];
    if (tid < Pn) kc_[tid] = kern[tid];

    // stage a 32-row x 128-k slice of s1, pre-split, into buf
    auto stageA = [&](int buf, int kb) {
        int r = tid >> 5, k = (tid & 31) * 4;
        float4 v = *(const float4*)(s1b + (size_t)r * Dn + kb + k);
        short2 p0 = bf16split(v.x), p1 = bf16split(v.y),
               p2 = bf16split(v.z), p3 = bf16split(v.w);
        short4 h; h.x = p0.x; h.y = p1.x; h.z = p2.x; h.w = p3.x;
        short4 l; l.x = p0.y; l.y = p1.y; l.z = p2.y; l.w = p3.y;
        *(short4*)&Ah[buf][r][k] = h;
        *(short4*)&Al[buf][r][k] = l;
    };

    // ---------------- Phase A: S = s1_tile @ s2^T (K = D = 1024) -----------
    f32x4 accA[2][2];
#pragma unroll
    for (int m = 0; m < 2; ++m)
#pragma unroll
        for (int t = 0; t < 2; ++t) accA[m][t] = (f32x4){0.f, 0.f, 0.f, 0.f};

    stageA(0, 0);
    __syncthreads();

    for (int kb = 0; kb < Dn; kb += 128) {
        int cur = (kb >> 7) & 1;
        if (kb + 128 < Dn) stageA(cur ^ 1, kb + 128);
#pragma unroll
        for (int ks = 0; ks < 128; ks += 32) {
            bf16x8 ah[2], al[2];
#pragma unroll
            for (int m = 0; m < 2; ++m) {
                ah[m] = *(const bf16x8*)&Ah[cur][m * 16 + lr][ks + lg * 8];
                al[m] = *(const bf16x8*)&Al[cur][m * 16 + lr][ks + lg * 8];
            }
#pragma unroll
            for (int t = 0; t < 2; ++t) {
                int l2 = (w * 2 + t) * 16 + lr;
                size_t off = (s2row0 + l2) * Dn + kb + ks + lg * 8;
                bf16x8 bh = *(const bf16x8*)(s2nh + off);
                bf16x8 bl = *(const bf16x8*)(s2nl + off);
#pragma unroll
                for (int m = 0; m < 2; ++m) {
                    accA[m][t] = __builtin_amdgcn_mfma_f32_16x16x32_bf16(ah[m], bh, accA[m][t], 0, 0, 0);
                    accA[m][t] = __builtin_amdgcn_mfma_f32_16x16x32_bf16(ah[m], bl, accA[m][t], 0, 0, 0);
                    accA[m][t] = __builtin_amdgcn_mfma_f32_16x16x32_bf16(al[m], bh, accA[m][t], 0, 0, 0);
                }
            }
        }
        __syncthreads();
    }
    // D layout: col = lane&15, row = (lane>>4)*4 + reg  [measured m89/m91]
#pragma unroll
    for (int m = 0; m < 2; ++m)
#pragma unroll
        for (int t = 0; t < 2; ++t)
#pragma unroll
            for (int reg = 0; reg < 4; ++reg)
                Sr[m * 16 + lg * 4 + reg][(w * 2 + t) * 16 + lr] = accA[m][t][reg];
    __syncthreads();

    // ---------------- convert to cos + row sums ----------------------------
    {
        int r = tid >> 5, part = tid & 31;
        float n1v = n1c[r];
        float s = 0.f;
#pragma unroll 8
        for (int j = 0; j < 16; ++j) {
            int l2 = part + 32 * j;
            float d = Sr[r][l2];
            float c = d / fmaxf(n1v * n2c[l2], 1e-8f);
            Sr[r][l2] = c;
            s += c;
        }
        red[r][part] = s;
    }
    __syncthreads();
    if (tid < 32) {
        float s = 0.f;
#pragma unroll
        for (int j = 0; j < 32; ++j) s += red[tid][j];
        scl[tid] = s + 1e-8f;
    }
    __syncthreads();

    // ---------------- Phase B: ws = cos @ s2 (K = L2 = 512) ----------------
    f32x4 accB[2][4];
#pragma unroll
    for (int m = 0; m < 2; ++m)
#pragma unroll
        for (int t = 0; t < 4; ++t) accB[m][t] = (f32x4){0.f, 0.f, 0.f, 0.f};

    for (int kc = 0; kc < Ln; kc += 32) {
        bf16x8 ah[2], al[2];
#pragma unroll
        for (int m = 0; m < 2; ++m) {
            const float* ap = &Sr[m * 16 + lr][kc + lg * 8];
            float4 v0 = *(const float4*)ap;
            float4 v1 = *(const float4*)(ap + 4);
            float f[8] = {v0.x, v0.y, v0.z, v0.w, v1.x, v1.y, v1.z, v1.w};
#pragma unroll
            for (int j = 0; j < 8; ++j) {
                short2 p = bf16split(f[j]);
                ah[m][j] = p.x;
                al[m][j] = p.y;
            }
        }
#pragma unroll
        for (int t = 0; t < 4; ++t) {
            int d = (w * 4 + t) * 16 + lr;
            size_t off = (s2trow0 + d) * Ln + kc + lg * 8;
            bf16x8 bh = *(const bf16x8*)(s2th + off);
            bf16x8 bl = *(const bf16x8*)(s2tl + off);
#pragma unroll
            for (int m = 0; m < 2; ++m) {
                accB[m][t] = __builtin_amdgcn_mfma_f32_16x16x32_bf16(ah[m], bh, accB[m][t], 0, 0, 0);
                accB[m][t] = __builtin_amdgcn_mfma_f32_16x16x32_bf16(ah[m], bl, accB[m][t], 0, 0, 0);
                accB[m][t] = __builtin_amdgcn_mfma_f32_16x16x32_bf16(al[m], bh, accB[m][t], 0, 0, 0);
            }
        }
    }

    // ---------------- fold ws into ss/sd, reduce, epilogue -----------------
    float ss[2][4], sd[2][4];
#pragma unroll
    for (int m = 0; m < 2; ++m)
#pragma unroll
        for (int reg = 0; reg < 4; ++reg) { ss[m][reg] = 0.f; sd[m][reg] = 0.f; }

#pragma unroll
    for (int m = 0; m < 2; ++m)
#pragma unroll
        for (int t = 0; t < 4; ++t) {
            int d = (w * 4 + t) * 16 + lr;
#pragma unroll
            for (int reg = 0; reg < 4; ++reg) {
                int row = m * 16 + lg * 4 + reg;
                float wv = accB[m][t][reg];
                ss[m][reg] = fmaf(wv, wv, ss[m][reg]);
                float x = s1b[(size_t)row * Dn + d];
                sd[m][reg] = fmaf(x, wv, sd[m][reg]);
            }
        }
#pragma unroll
    for (int m = 0; m < 2; ++m)
#pragma unroll
        for (int reg = 0; reg < 4; ++reg) {
#pragma unroll
            for (int msk = 8; msk; msk >>= 1) {
                ss[m][reg] += __shfl_xor(ss[m][reg], msk, 64);
                sd[m][reg] += __shfl_xor(sd[m][reg], msk, 64);
            }
        }
    if (lr == 0) {
#pragma unroll
        for (int m = 0; m < 2; ++m)
#pragma unroll
            for (int reg = 0; reg < 4; ++reg) {
                redS[m * 16 + lg * 4 + reg][w] = ss[m][reg];
                redD[m * 16 + lg * 4 + reg][w] = sd[m][reg];
            }
    }
    __syncthreads();

    if (tid < 32 * Pn) {
        int r = tid / Pn, p = tid % Pn;
        float ssT = 0.f, sdT = 0.f;
#pragma unroll
        for (int j = 0; j < 16; ++j) { ssT += redS[r][j]; sdT += redD[r][j]; }
        float n1v = n1c[r];
        float scv = scl[r];
        float kp  = kc_[p];
        float kp2 = kp * kp;
        float wsn = sqrtf(ssT);
        float dot2  = kp2 * sdT / scv;
        float denom = fmaxf(kp2 * n1v * wsn / fabsf(scv), 1e-8f);
        out[(size_t)(b * Ln + R0 + r) * Pn + p] = dot2 / denom;
    }
}

// ===========================================================================
// fp32 fallback — used only if ws_size can't hold the bf16 arrays.
// ===========================================================================
#define Mr 16
#define LD2 516

__global__ __launch_bounds__(256, 2) void fused_kernel(const float* __restrict__ s1,
                                                       const float* __restrict__ s2,
                                                       const float* __restrict__ kern,
                                                       const float* __restrict__ nrm,
                                                       float* __restrict__ out) {
    __shared__ float Sr[Mr][LD2];
    __shared__ float s2t[16][LD2];
    __shared__ float ab[16][16];
    __shared__ float n2c[Ln];
    __shared__ float n1c[Mr];
    __shared__ float scl[Mr];
    __shared__ float red[Mr][16];
    __shared__ float redS[Mr][2];
    __shared__ float redD[Mr][2];
    __shared__ float kc_[16];

    const int tid  = threadIdx.x;
    const int w    = tid >> 6;
    const int lane = tid & 63;
    const int rg   = w & 1;
    const int cg   = w >> 1;

    const int wg = ((blockIdx.x & 7) << 6) | (blockIdx.x >> 3);
    const int b  = wg >> 5;
    const int R0 = (wg & 31) * Mr;

    const float* s1b = s1 + ((size_t)b * Ln + R0) * Dn;
    const float* s2g = s2 + (size_t)b * Ln * Dn;

    if (tid < Mr) n1c[tid] = nrm[b * Ln + R0 + tid];
    n2c[tid]       = nrm[Bn * Ln + b * Ln + tid];
    n2c[tid + 256] = nrm[Bn * Ln + b * Ln + tid + 256];
    if (tid < Pn) kc_[tid] = kern[tid];

    float accA[8][4];
#pragma unroll
    for (int e = 0; e < 8; ++e)
#pragma unroll
        for (int c = 0; c < 4; ++c) accA[e][c] = 0.f;

    for (int kc = 0; kc < Dn; kc += 16) {
        __syncthreads();
        {
            int r = tid >> 4, k = tid & 15;
            ab[k][r] = s1b[(size_t)r * Dn + kc + k];
        }
        {
            int p = tid >> 2, j = tid & 3;
#pragma unroll
            for (int ri = 0; ri < 8; ++ri) {
                int l2 = ri * 64 + p;
                float4 v = *(const float4*)(s2g + (size_t)l2 * Dn + kc + 4 * j);
                s2t[4 * j + 0][l2] = v.x;
                s2t[4 * j + 1][l2] = v.y;
                s2t[4 * j + 2][l2] = v.z;
                s2t[4 * j + 3][l2] = v.w;
            }
        }
        __syncthreads();
#pragma unroll
        for (int k = 0; k < 16; ++k) {
            float4 a0 = *(const float4*)&ab[k][rg * 8];
            float4 a1 = *(const float4*)&ab[k][rg * 8 + 4];
            float4 bv = *(const float4*)&s2t[k][cg * 256 + 4 * lane];
            float aa[8] = {a0.x, a0.y, a0.z, a0.w, a1.x, a1.y, a1.z, a1.w};
            float bb[4] = {bv.x, bv.y, bv.z, bv.w};
#pragma unroll
            for (int e = 0; e < 8; ++e)
#pragma unroll
                for (int c = 0; c < 4; ++c)
                    accA[e][c] = fmaf(aa[e], bb[c], accA[e][c]);
        }
    }
#pragma unroll
    for (int e = 0; e < 8; ++e)
        *(float4*)&Sr[rg * 8 + e][cg * 256 + 4 * lane] =
            make_float4(accA[e][0], accA[e][1], accA[e][2], accA[e][3]);
    __syncthreads();

    {
        int r = tid >> 4, part = tid & 15;
        float n1v = n1c[r];
        float s = 0.f;
#pragma unroll 8
        for (int j = 0; j < 32; ++j) {
            int l2 = part + 16 * j;
            float d = Sr[r][l2];
            float c = d / fmaxf(n1v * n2c[l2], 1e-8f);
            Sr[r][l2] = c;
            s += c;
        }
        red[r][part] = s;
    }
    __syncthreads();
    if (tid < Mr) {
        float s = 0.f;
#pragma unroll
        for (int j = 0; j < 16; ++j) s += red[tid][j];
        scl[tid] = s + 1e-8f;
    }

    float ss[8] = {0.f, 0.f, 0.f, 0.f, 0.f, 0.f, 0.f, 0.f};
    float sd[8] = {0.f, 0.f, 0.f, 0.f, 0.f, 0.f, 0.f, 0.f};

    for (int dh = 0; dh < Dn; dh += 512) {
        float accB[8][4];
#pragma unroll
        for (int e = 0; e < 8; ++e)
#pragma unroll
            for (int c = 0; c < 4; ++c) accB[e][c] = 0.f;

        for (int l2c = 0; l2c < Ln; l2c += 16) {
            __syncthreads();
            {
                int l2 = tid >> 4, r = tid & 15;
                ab[l2][r] = Sr[r][l2c + l2];
            }
            {
                int l2 = tid >> 4, q = tid & 15;
                const float* srcrow = s2g + (size_t)(l2c + l2) * Dn + dh;
#pragma unroll
                for (int j = 0; j < 8; ++j)
                    *(float4*)&s2t[l2][q * 4 + j * 64] =
                        *(const float4*)(srcrow + q * 4 + j * 64);
            }
            __syncthreads();
#pragma unroll
            for (int k = 0; k < 16; ++k) {
                float4 a0 = *(const float4*)&ab[k][rg * 8];
                float4 a1 = *(const float4*)&ab[k][rg * 8 + 4];
                float4 bv = *(const float4*)&s2t[k][cg * 256 + 4 * lane];
                float aa[8] = {a0.x, a0.y, a0.z, a0.w, a1.x, a1.y, a1.z, a1.w};
                float bb[4] = {bv.x, bv.y, bv.z, bv.w};
#pragma unroll
                for (int e = 0; e < 8; ++e)
#pragma unroll
                    for (int c = 0; c < 4; ++c)
                        accB[e][c] = fmaf(aa[e], bb[c], accB[e][c]);
            }
        }
#pragma unroll
        for (int e = 0; e < 8; ++e) {
            const float* s1row = s1b + (size_t)(rg * 8 + e) * Dn + dh + cg * 256 + 4 * lane;
            float4 x = *(const float4*)s1row;
            float xx[4] = {x.x, x.y, x.z, x.w};
#pragma unroll
            for (int c = 0; c < 4; ++c) {
                float wv = accB[e][c];
                ss[e] = fmaf(wv, wv, ss[e]);
                sd[e] = fmaf(xx[c], wv, sd[e]);
            }
        }
    }

#pragma unroll
    for (int e = 0; e < 8; ++e) {
#pragma unroll
        for (int m = 32; m; m >>= 1) {
            ss[e] += __shfl_xor(ss[e], m, 64);
            sd[e] += __shfl_xor(sd[e], m, 64);
        }
    }
    if (lane == 0) {
#pragma unroll
        for (int e = 0; e < 8; ++e) {
            redS[rg * 8 + e][cg] = ss[e];
            redD[rg * 8 + e][cg] = sd[e];
        }
    }
    __syncthreads();

    if (tid < Mr * Pn) {
        int r = tid / Pn, p = tid % Pn;
        float ssT = redS[r][0] + redS[r][1];
        float sdT = redD[r][0] + redD[r][1];
        float n1v = n1c[r];
        float scv = scl[r];
        float kp  = kc_[p];
        float kp2 = kp * kp;
        float wsn = sqrtf(ssT);
        float dot2  = kp2 * sdT / scv;
        float denom = fmaxf(kp2 * n1v * wsn / fabsf(scv), 1e-8f);
        out[(size_t)(b * Ln + R0 + r) * Pn + p] = dot2 / denom;
    }
}

extern "C" void kernel_launch(void* const* d_in, const int* in_sizes, int n_in,
                              void* d_out, int out_size, void* d_ws, size_t ws_size,
                              hipStream_t stream) {
    const float* s1   = (const float*)d_in[0];
    const float* s2   = (const float*)d_in[1];
    const float* kern = (const float*)d_in[2];
    float* out = (float*)d_out;

    char* w = (char*)d_ws;
    float* nrm = (float*)w;                               // 64 KB
    const size_t SZ1 = (size_t)Bn * Ln * Dn * sizeof(short);  // 16 MB per array
    short* s2nh = (short*)(w + 65536);
    short* s2nl = (short*)(w + 65536 + SZ1);
    short* s2th = (short*)(w + 65536 + 2 * SZ1);
    short* s2tl = (short*)(w + 65536 + 3 * SZ1);
    const size_t NEED = 65536 + 4 * SZ1;                  // ~64.1 MB

    hipLaunchKernelGGL(norms_kernel, dim3((Bn * Ln * 2) / 4), dim3(256), 0, stream,
                       s1, s2, nrm);

    if (ws_size >= NEED) {
        // MFMA path
        hipLaunchKernelGGL(prep_s2_kernel, dim3(Bn * 8 * 16), dim3(256), 0, stream,
                           s2, s2nh, s2nl, s2th, s2tl);
        hipLaunchKernelGGL(mfma_fused_kernel, dim3(Bn * (Ln / 32)), dim3(1024), 0, stream,
                           s1, kern, nrm, s2nh, s2nl, s2th, s2tl, out);
    } else {
        // fp32 fallback
        hipLaunchKernelGGL(fused_kernel, dim3(Bn * (Ln / Mr)), dim3(256), 0, stream,
                           s1, s2, kern, nrm, out);
    }
}